// Round 10
// baseline (6318.785 us; speedup 1.0000x reference)
//
#include <hip/hip_runtime.h>
#include <hip/hip_fp16.h>
#include <math.h>

// Problem constants
#define BATCH 256
#define TSEQ  512
#define FEAT  64
#define NU1   256
#define NU2   128

// half2-element offsets of packed fp16 weight planes inside d_ws.
// Quad-pair planes, K-split-contiguous chunk order (one chunk = 4 half2 row-pairs):
// GRU1 plane (per gate): [2 kh][20 chunks][256 cols][4]
//   chunks 0..3  = x rows (kh half: feats kh*32..+31  = act1 pairs kh*16+0..15)
//   chunks 4..19 = h1 rows (kh half: units kh*128..+127 = act1 pairs 32+kh*64+0..63)
// GRU2 plane (per gate): [4 kq][12 chunks][128 cols][4]
//   chunks 0..7  = h1 rows (kq quarter: units kq*64..+63 = act1 pairs 32+kq*32+0..31)
//   chunks 8..11 = h2 rows (kq quarter: units kq*32..+31 = act2 pairs kq*16+0..15)
#define G1Z_OFF 0
#define G1R_OFF 40960
#define G1H_OFF 81920
#define G2Z_OFF 122880
#define G2R_OFF 147456
#define G2H_OFF 172032
#define TOTAL_H2 196608   // 786,432 bytes of d_ws

// uint4-unit plane offsets (half2 offset / 4)
#define G1Z_U4 0
#define G1R_U4 10240
#define G1H_U4 20480
#define G2Z_U4 30720
#define G2R_U4 36864
#define G2H_U4 43008

// dynamic LDS: 8 wave-private staging rings (8 x 12,288 B) + GRU1 x-part park (49,152 B)
#define LDS_PARK_BYTES (9216 * 16)   // 147,456 B

typedef _Float16 h2f __attribute__((ext_vector_type(2)));
typedef __attribute__((address_space(3))) void lds_void;
typedef const __attribute__((address_space(1))) void glob_void;
// one DMA instr: 64 lanes x 16 B = 1 KB global -> LDS, no VGPR landing
#define GLDS16(src, dst) \
    __builtin_amdgcn_global_load_lds((glob_void*)(src), (lds_void*)(dst), 16, 0, 0)

__device__ __forceinline__ float sigmoid_f(float v) {
    return 1.0f / (1.0f + __expf(-v));
}
__device__ __forceinline__ float tanh_f(float v) {
    float c = fminf(fmaxf(v, -15.0f), 15.0f);
    float e = __expf(2.0f * c);
    return (e - 1.0f) / (e + 1.0f);
}

__device__ __forceinline__ h2f bch2(unsigned int u) {
    return __builtin_bit_cast(h2f, u);
}
__device__ __forceinline__ unsigned int pack2(float a, float b) {
    h2f v;
    v.x = (_Float16)a;
    v.y = (_Float16)b;
    return __builtin_bit_cast(unsigned int, v);
}

// acc += dot of 4 half2 pairs (8 fp16 weights x 8 fp16 activations), fp32 accum
__device__ __forceinline__ void dot4(float& acc, uint4 w, uint4 a) {
    acc = __builtin_amdgcn_fdot2(bch2(w.x), bch2(a.x), acc, false);
    acc = __builtin_amdgcn_fdot2(bch2(w.y), bch2(a.y), acc, false);
    acc = __builtin_amdgcn_fdot2(bch2(w.z), bch2(a.z), acc, false);
    acc = __builtin_amdgcn_fdot2(bch2(w.w), bch2(a.w), acc, false);
}

// ---------------- weight packing (fp32 -> fp16 quad-pair planes) ----------------
// R3-proven layout: GRU1 [2 kh][20 chunks], GRU2 [4 kq][12 chunks]. UNCHANGED.
__global__ void pack_weights(const float* __restrict__ k1, const float* __restrict__ r1,
                             const float* __restrict__ k2, const float* __restrict__ r2,
                             __half2* __restrict__ ws)
{
    int idx = blockIdx.x * 256 + threadIdx.x;
    if (idx >= TOTAL_H2) return;
    float a, b;
    if (idx < G2Z_OFF) {
        int plane = idx / 40960;       // 0=z 1=r 2=h
        int rem   = idx % 40960;       // = cc*1024 + col*4 + q
        int cc    = rem >> 10;         // 0..39
        int col   = (rem >> 2) & 255;
        int q     = rem & 3;
        int kh    = cc / 20;
        int c     = cc - kh * 20;
        int g     = plane * 256 + col; // gate-column in [0,768)
        int pair  = (c < 4) ? ((kh * 4 + c) * 4 + q)
                            : (32 + (kh * 16 + (c - 4)) * 4 + q);
        int row0  = pair * 2;
        if (row0 < 64) { a = k1[row0 * 768 + g];        b = k1[(row0 + 1) * 768 + g]; }
        else           { a = r1[(row0 - 64) * 768 + g]; b = r1[(row0 - 63) * 768 + g]; }
    } else {
        int idx2  = idx - G2Z_OFF;
        int plane = idx2 / 24576;
        int rem   = idx2 % 24576;      // = cc*512 + col*4 + q
        int cc    = rem >> 9;          // 0..47
        int col   = (rem >> 2) & 127;
        int q     = rem & 3;
        int kq    = cc / 12;
        int c     = cc - kq * 12;
        int g     = plane * 128 + col; // gate-column in [0,384)
        int pair  = (c < 8) ? ((kq * 8 + c) * 4 + q)
                            : (128 + (kq * 4 + (c - 8)) * 4 + q);
        int row0  = pair * 2;
        if (row0 < 256) { a = k2[row0 * 384 + g];         b = k2[(row0 + 1) * 384 + g]; }
        else            { a = r2[(row0 - 256) * 384 + g]; b = r2[(row0 - 255) * 384 + g]; }
    }
    __half2 h;
    h.x = __float2half_rn(a);
    h.y = __float2half_rn(b);
    ws[idx] = h;
}

// 2-deep K-segment: NAMED A/B double buffer, #pragma unroll 1 (R1/R2 spill lesson).
template <int COLS, int NCH>
__device__ __forceinline__ void seg3(const uint4* __restrict__ pz,
                                     const uint4* __restrict__ pr,
                                     const uint4* __restrict__ ph,
                                     const unsigned int* __restrict__ act,
                                     float& az, float& ar, float& a3)
{
    static_assert(NCH % 4 == 0, "NCH must be a multiple of 4");
    uint4 a_z0 = pz[0], a_z1 = pz[COLS];
    uint4 a_r0 = pr[0], a_r1 = pr[COLS];
    uint4 a_h0 = ph[0], a_h1 = ph[COLS];
    #pragma unroll 1
    for (int c = 0; c < NCH; c += 4) {
        const uint4* qz = pz + 2 * COLS;
        const uint4* qr = pr + 2 * COLS;
        const uint4* qh = ph + 2 * COLS;
        uint4 b_z0 = qz[0], b_z1 = qz[COLS];
        uint4 b_r0 = qr[0], b_r1 = qr[COLS];
        uint4 b_h0 = qh[0], b_h1 = qh[COLS];
        const uint4 v0 = *(const uint4*)(act);
        const uint4 v1 = *(const uint4*)(act + 4);
        dot4(az, a_z0, v0); dot4(ar, a_r0, v0); dot4(a3, a_h0, v0);
        dot4(az, a_z1, v1); dot4(ar, a_r1, v1); dot4(a3, a_h1, v1);
        pz += 4 * COLS; pr += 4 * COLS; ph += 4 * COLS;
        if (c + 4 < NCH) {
            a_z0 = pz[0]; a_z1 = pz[COLS];
            a_r0 = pr[0]; a_r1 = pr[COLS];
            a_h0 = ph[0]; a_h1 = ph[COLS];
        }
        const uint4 v2 = *(const uint4*)(act + 8);
        const uint4 v3 = *(const uint4*)(act + 12);
        act += 16;
        dot4(az, b_z0, v2); dot4(ar, b_r0, v2); dot4(a3, b_h0, v2);
        dot4(az, b_z1, v3); dot4(ar, b_r1, v3); dot4(a3, b_h1, v3);
    }
}

// 2-chunk straight-line segment (x-part: LDS-park half + global half)
template <int COLS>
__device__ __forceinline__ void seg_pair(const uint4* __restrict__ pz,
                                         const uint4* __restrict__ pr,
                                         const uint4* __restrict__ ph,
                                         const unsigned int* __restrict__ act,
                                         float& az, float& ar, float& a3)
{
    uint4 z0 = pz[0], z1 = pz[COLS];
    uint4 r0 = pr[0], r1 = pr[COLS];
    uint4 h0 = ph[0], h1 = ph[COLS];
    const uint4 v0 = *(const uint4*)(act);
    const uint4 v1 = *(const uint4*)(act + 4);
    dot4(az, z0, v0); dot4(ar, r0, v0); dot4(a3, h0, v0);
    dot4(az, z1, v1); dot4(ar, r1, v1); dot4(a3, h1, v1);
}

// 256 WGs x 512 threads (8 waves/CU), one batch row per WG.
// R10: GRU1 h-part (384 KB/step, 60% of global loads) streamed via
// global_load_lds into WAVE-PRIVATE 12 KB LDS rings (2 slots x 6 KB unit =
// 2 chunks x 3 gates x the wave's 32 cols x 2 kh). Weights are time-invariant:
// after consuming unit u, the wave re-issues the SAME slot's DMA for unit u+2
// (== next step's data). Mid-step safety: counted `s_waitcnt vmcnt(6)` per
// unit (in-order vmcnt retirement => safe under any x-prefetch interleaving);
// cross-step safety: the compiler's vmcnt(0) drain before the per-step
// __syncthreads. No cross-wave sync added (rings private). Frees the 48 VGPRs
// of G1h register buffers (VGPR wall: threads x VGPR <= 65536, R4/R5/R6).
// GRU2-h2 park dropped (back to R3 global path) to fit rings; x-park kept.
__global__ __launch_bounds__(512, 2)
void gru_fused(const float* __restrict__ x,
               const float* __restrict__ b1, const float* __restrict__ b2,
               const float* __restrict__ w3, const float* __restrict__ b3,
               const float* __restrict__ w4, const float* __restrict__ b4,
               const float* __restrict__ w5, const float* __restrict__ b5,
               const unsigned int* __restrict__ wp,
               float* __restrict__ out)
{
    // dynamic LDS: [0..6143]=8 wave rings (768 uint4 each), [6144..9215]=x-park
    extern __shared__ __align__(16) uint4 lwdyn[];
    uint4* stg4 = lwdyn;
    uint4* lw1  = lwdyn + 6144;
    // fp16 activation pair buffers (uint = one half2), double-buffered. (static)
    __shared__ __align__(16) unsigned int act1[2][160];   // [0..31]=x(t), [32..159]=h1
    __shared__ __align__(16) unsigned int act2[2][64];    // h2
    __shared__ __align__(16) unsigned int act1s[2][160];  // skewed h1 replica (kq*40)
    __shared__ float h2fin[NU2];
    __shared__ float d3[64];
    __shared__ float d4[32];

    const int tid  = threadIdx.x;
    const int row  = blockIdx.x;
    const int j    = tid >> 1;      // GRU1 column (0..255)
    const int kh   = tid & 1;       // GRU1 K-half
    const int c2   = tid >> 2;      // GRU2 column (0..127)
    const int kq   = tid & 3;       // GRU2 K-quarter
    const int wid  = tid >> 6;      // wave id (0..7)
    const int lane = tid & 63;

    const uint4* wp4 = (const uint4*)wp;
    const char*  wpb = (const char*)wp;

    // ---- staging ring setup (wave-private) ----
    // staged block (slot, g, p): 1 KB; lane l' holds [kh=l'>>5][col 32*wid+(l'&31)]
    // consumer thread (lane l): kh=l&1, col-in-wave=l>>1 -> staged index below
    const int    cidx = (lane & 1) * 32 + (lane >> 1);
    const uint4* stgw = stg4 + wid * 768;
    char*        stgB = (char*)stg4 + wid * 12288;
    // per-lane DMA source bases: gate plane + h-part start + lane's (kh,col) slot
    const size_t loff = ((size_t)((lane >> 5) * 20 + 4) * 256 +
                         (size_t)(wid * 32 + (lane & 31))) * 16;
    const char* p1zS = wpb + (size_t)G1Z_U4 * 16 + loff;
    const char* p1rS = wpb + (size_t)G1R_U4 * 16 + loff;
    const char* p1hS = wpb + (size_t)G1H_U4 * 16 + loff;

    // initial fill: units 0 (slot 0) and 1 (slot 1); drained by the barrier below
    #pragma unroll
    for (int uu = 0; uu < 2; ++uu) {
        char* db = stgB + uu * 6144;
        const size_t c0 = (size_t)(uu * 2) * 4096;
        GLDS16(p1zS + c0,        db);
        GLDS16(p1zS + c0 + 4096, db + 1024);
        GLDS16(p1rS + c0,        db + 2048);
        GLDS16(p1rS + c0 + 4096, db + 3072);
        GLDS16(p1hS + c0,        db + 4096);
        GLDS16(p1hS + c0 + 4096, db + 5120);
    }

    // ---- x-part park (R9-proven lane-linear layout) ----
    for (int i = tid; i < 3072; i += 512) {
        int cg = i >> 9;
        int c  = cg / 3, g = cg - 3 * c;
        lw1[i] = wp4[G1Z_U4 + g * 10240 + (kh * 20 + c) * 256 + j];
    }

    for (int i = tid; i < 2 * 160; i += 512) (&act1[0][0])[i]  = 0u;
    for (int i = tid; i < 2 * 64;  i += 512) (&act2[0][0])[i]  = 0u;
    for (int i = tid; i < 2 * 160; i += 512) (&act1s[0][0])[i] = 0u;

    // GRU1 biases (z,r folded; h split for reset_after), counted once via kh mask
    const float bm1  = (kh == 0) ? 1.0f : 0.0f;
    const float bz1  = (b1[j] + b1[768 + j]) * bm1;
    const float br1  = (b1[256 + j] + b1[1024 + j]) * bm1;
    const float bxh1 = b1[512 + j] * bm1;
    const float brh1 = b1[1280 + j] * bm1;
    // GRU2 biases, counted once via kq mask
    const float bm2  = (kq == 0) ? 1.0f : 0.0f;
    const float bz2  = (b2[c2] + b2[384 + c2]) * bm2;
    const float br2  = (b2[128 + c2] + b2[512 + c2]) * bm2;
    const float bxh2 = b2[256 + c2] * bm2;
    const float brh2 = b2[640 + c2] * bm2;

    // global weight bases (register path)
    const uint4* g1z = wp4 + G1Z_U4 + (kh * 20) * 256 + j;
    const uint4* g1r = wp4 + G1R_U4 + (kh * 20) * 256 + j;
    const uint4* g1h = wp4 + G1H_U4 + (kh * 20) * 256 + j;
    const uint4* g2z = wp4 + G2Z_U4 + (kq * 12) * 128 + c2;
    const uint4* g2r = wp4 + G2R_U4 + (kq * 12) * 128 + c2;
    const uint4* g2h = wp4 + G2H_U4 + (kq * 12) * 128 + c2;
    // x-park base (lane-linear: gate stride 512, chunk stride 1536 uint4)
    const uint4* l1 = lw1 + tid;

    __syncthreads();   // park + initial DMA fill (compiler drains vmcnt) + zeros

    if (tid < FEAT) {
        float x0 = x[(size_t)row * TSEQ * FEAT + tid];
        float xb = __shfl_xor(x0, 1);
        if ((tid & 1) == 0) act1[0][tid >> 1] = pack2(x0, xb);
    }
    __syncthreads();

    float hp1 = 0.0f;   // h1 previous state, col j (redundant on the lane pair)
    float hp2 = 0.0f;   // h2 previous state, col c2 (redundant on the lane quad)

    for (int t = 0; t < TSEQ; ++t) {
        const int cur = t & 1, nb = cur ^ 1;

        // prefetch next x into registers (packed to LDS before the barrier)
        float xpre = 0.0f;
        if (t + 1 < TSEQ && tid < FEAT)
            xpre = x[(size_t)row * TSEQ * FEAT + (t + 1) * FEAT + tid];

        // ---------------- GRU1: reads act1[cur]; writes act1[nb] ----------------
        float az = bz1, ar = br1, aA = bxh1, aB = brh1;
        // x-part: chunks 0-1 from park, chunks 2-3 from global
        seg_pair<1536>(l1, l1 + 512, l1 + 1024, &act1[cur][kh * 16], az, ar, aA);
        seg_pair<256>(g1z + 2 * 256, g1r + 2 * 256, g1h + 2 * 256,
                      &act1[cur][kh * 16 + 8], az, ar, aA);
        // h-part: 8 units of 2 chunks from the wave-private staged ring
        {
            const unsigned int* ap = &act1[cur][32 + kh * 64];
            #pragma unroll
            for (int u = 0; u < 8; ++u) {
                const int slot = u & 1;
                // slot's refill was issued >=1 unit (or one barrier) ago:
                // wait until at most the newest refill (6 instrs) is outstanding
                asm volatile("s_waitcnt vmcnt(6)" ::: "memory");
                __builtin_amdgcn_sched_barrier(0);
                const uint4* sp = stgw + slot * 384;
                uint4 w0z = sp[cidx],       w0r = sp[128 + cidx], w0h = sp[256 + cidx];
                uint4 w1z = sp[64 + cidx],  w1r = sp[192 + cidx], w1h = sp[320 + cidx];
                const uint4 a0 = *(const uint4*)(ap + u * 8);
                const uint4 a1 = *(const uint4*)(ap + u * 8 + 4);
                dot4(az, w0z, a0); dot4(ar, w0r, a0); dot4(aB, w0h, a0);
                dot4(az, w1z, a1); dot4(ar, w1r, a1); dot4(aB, w1h, a1);
                __builtin_amdgcn_sched_barrier(0);   // dots (ds-dependent) before refill
                // refill same slot with unit (u+2)&7 -- identical bytes next step
                const size_t c0 = (size_t)(((u + 2) & 7) * 2) * 4096;
                char* db = stgB + slot * 6144;
                GLDS16(p1zS + c0,        db);
                GLDS16(p1zS + c0 + 4096, db + 1024);
                GLDS16(p1rS + c0,        db + 2048);
                GLDS16(p1rS + c0 + 4096, db + 3072);
                GLDS16(p1hS + c0,        db + 4096);
                GLDS16(p1hS + c0 + 4096, db + 5120);
                __builtin_amdgcn_sched_barrier(0);
            }
        }
        az += __shfl_xor(az, 1);
        ar += __shfl_xor(ar, 1);
        aA += __shfl_xor(aA, 1);
        aB += __shfl_xor(aB, 1);
        {
            const float z  = sigmoid_f(az);
            const float rg = sigmoid_f(ar);
            const float hh = tanh_f(aA + rg * aB);
            const float hn = z * hp1 + (1.0f - z) * hh;
            hp1 = hn;
            const float hnb = __shfl_xor(hn, 2);   // partner column (2m+1) on lane 4m
            if ((tid & 3) == 0) {
                const unsigned int pk = pack2(hn, hnb);
                const int p = tid >> 2;                    // pair index 0..127
                act1[nb][32 + p] = pk;
                act1s[nb][(p >> 5) * 40 + (p & 31)] = pk;  // skewed replica for GRU2
            }
        }
        if (t + 1 < TSEQ && tid < FEAT) {
            float xb = __shfl_xor(xpre, 1);
            if ((tid & 1) == 0) act1[nb][tid >> 1] = pack2(xpre, xb);
        }
        __syncthreads();   // THE one barrier (also drains this step's ring DMAs)

        // ---------------- GRU2: reads act1s[nb] h-part, act2[cur]; writes act2[nb] ----------------
        float az2 = bz2, ar2 = br2, aA2 = bxh2, aB2 = brh2;
        // h1-part: 8 chunks from global, act from skewed replica (bank-spread)
        seg3<128, 8>(g2z, g2r, g2h, &act1s[nb][kq * 40], az2, ar2, aA2);
        // h2-part: 4 chunks from global (R3 path; park dropped for ring space)
        seg3<128, 4>(g2z + 8 * 128, g2r + 8 * 128, g2h + 8 * 128,
                     &act2[cur][kq * 16], az2, ar2, aB2);
        az2 += __shfl_xor(az2, 1); az2 += __shfl_xor(az2, 2);
        ar2 += __shfl_xor(ar2, 1); ar2 += __shfl_xor(ar2, 2);
        aA2 += __shfl_xor(aA2, 1); aA2 += __shfl_xor(aA2, 2);
        aB2 += __shfl_xor(aB2, 1); aB2 += __shfl_xor(aB2, 2);
        {
            const float z2v = sigmoid_f(az2);
            const float rg2 = sigmoid_f(ar2);
            const float hh2 = tanh_f(aA2 + rg2 * aB2);
            const float hn2 = z2v * hp2 + (1.0f - z2v) * hh2;
            hp2 = hn2;
            const float hnb2 = __shfl_xor(hn2, 4); // partner column (2m+1) on lane 8m
            if ((tid & 7) == 0) act2[nb][tid >> 3] = pack2(hn2, hnb2);
        }
        // no second barrier: next step's barrier covers act2[nb] visibility;
        // all WAR hazards are buffer-separated (same discipline as proven kernel)
    }

    if ((tid & 3) == 0) h2fin[c2] = hp2;   // final h2 state, fp32
    __syncthreads();

    // ---------------- dense head: h2 -> 64 -> 32 -> 24 ----------------
    if (tid < 64) {
        float a = b3[tid];
        #pragma unroll 4
        for (int u = 0; u < NU2; ++u) a += h2fin[u] * w3[u * 64 + tid];
        d3[tid] = a;
    }
    __syncthreads();
    if (tid < 32) {
        float a = b4[tid];
        #pragma unroll 4
        for (int u = 0; u < 64; ++u) a += d3[u] * w4[u * 32 + tid];
        d4[tid] = a;
    }
    __syncthreads();
    if (tid < 24) {
        float a = b5[tid];
        #pragma unroll 4
        for (int u = 0; u < 32; ++u) a += d4[u] * w5[u * 24 + tid];
        out[(size_t)row * 24 + tid] = a;
    }
}

extern "C" void kernel_launch(void* const* d_in, const int* in_sizes, int n_in,
                              void* d_out, int out_size, void* d_ws, size_t ws_size,
                              hipStream_t stream) {
    (void)in_sizes; (void)n_in; (void)ws_size; (void)out_size;
    const float* x  = (const float*)d_in[0];
    const float* k1 = (const float*)d_in[1];
    const float* r1 = (const float*)d_in[2];
    const float* b1 = (const float*)d_in[3];
    const float* k2 = (const float*)d_in[4];
    const float* r2 = (const float*)d_in[5];
    const float* b2 = (const float*)d_in[6];
    const float* w3 = (const float*)d_in[7];
    const float* b3 = (const float*)d_in[8];
    const float* w4 = (const float*)d_in[9];
    const float* b4 = (const float*)d_in[10];
    const float* w5 = (const float*)d_in[11];
    const float* b5 = (const float*)d_in[12];
    float* out = (float*)d_out;

    // Opt in to >64 KB dynamic LDS (host-side, executes at capture time).
    static bool lds_attr_set = false;
    if (!lds_attr_set) {
        (void)hipFuncSetAttribute((const void*)gru_fused,
                                  hipFuncAttributeMaxDynamicSharedMemorySize,
                                  LDS_PARK_BYTES);
        lds_attr_set = true;
    }

    hipLaunchKernelGGL(pack_weights, dim3((TOTAL_H2 + 255) / 256), dim3(256), 0, stream,
                       k1, r1, k2, r2, (__half2*)d_ws);
    hipLaunchKernelGGL(gru_fused, dim3(BATCH), dim3(512), LDS_PARK_BYTES, stream,
                       x, b1, b2, w3, b3, w4, b4, w5, b5,
                       (const unsigned int*)d_ws, out);
}

// Round 11
// 4742.020 us; speedup vs baseline: 1.3325x; 1.3325x over previous
//
#include <hip/hip_runtime.h>
#include <hip/hip_fp16.h>
#include <math.h>

// Problem constants
#define BATCH 256
#define TSEQ  512
#define FEAT  64
#define NU1   256
#define NU2   128

// half2-element offsets of packed fp16 weight planes inside d_ws.
// Quad-pair planes, K-split-contiguous chunk order (one chunk = 4 half2 row-pairs):
// GRU1 plane (per gate): [2 kh][20 chunks][256 cols][4]
//   chunks 0..3  = x rows (kh half: feats kh*32..+31  = act1 pairs kh*16+0..15)
//   chunks 4..19 = h1 rows (kh half: units kh*128..+127 = act1 pairs 32+kh*64+0..63)
// GRU2 plane (per gate): [4 kq][12 chunks][128 cols][4]
//   chunks 0..7  = h1 rows (kq quarter: units kq*64..+63 = act1 pairs 32+kq*32+0..31)
//   chunks 8..11 = h2 rows (kq quarter: units kq*32..+31 = act2 pairs kq*16+0..15)
#define G1Z_OFF 0
#define G1R_OFF 40960
#define G1H_OFF 81920
#define G2Z_OFF 122880
#define G2R_OFF 147456
#define G2H_OFF 172032
#define TOTAL_H2 196608   // 786,432 bytes of d_ws

// uint4-unit plane offsets (half2 offset / 4)
#define G1Z_U4 0
#define G1R_U4 10240
#define G1H_U4 20480
#define G2Z_U4 30720
#define G2R_U4 36864
#define G2H_U4 43008

// dynamic-LDS park size: GRU2 h2-part (6144 uint4) + GRU1 x-part (3072 uint4)
#define LDS_PARK_BYTES (9216 * 16)   // 147,456 B

typedef _Float16 h2f __attribute__((ext_vector_type(2)));

__device__ __forceinline__ float sigmoid_f(float v) {
    return 1.0f / (1.0f + __expf(-v));
}
__device__ __forceinline__ float tanh_f(float v) {
    float c = fminf(fmaxf(v, -15.0f), 15.0f);
    float e = __expf(2.0f * c);
    return (e - 1.0f) / (e + 1.0f);
}

__device__ __forceinline__ h2f bch2(unsigned int u) {
    return __builtin_bit_cast(h2f, u);
}
__device__ __forceinline__ unsigned int pack2(float a, float b) {
    h2f v;
    v.x = (_Float16)a;
    v.y = (_Float16)b;
    return __builtin_bit_cast(unsigned int, v);
}

// acc += dot of 4 half2 pairs (8 fp16 weights x 8 fp16 activations), fp32 accum
__device__ __forceinline__ void dot4(float& acc, uint4 w, uint4 a) {
    acc = __builtin_amdgcn_fdot2(bch2(w.x), bch2(a.x), acc, false);
    acc = __builtin_amdgcn_fdot2(bch2(w.y), bch2(a.y), acc, false);
    acc = __builtin_amdgcn_fdot2(bch2(w.z), bch2(a.z), acc, false);
    acc = __builtin_amdgcn_fdot2(bch2(w.w), bch2(a.w), acc, false);
}

// ---------------- weight packing (fp32 -> fp16 quad-pair planes) ----------------
// R3-proven layout: GRU1 [2 kh][20 chunks], GRU2 [4 kq][12 chunks]. UNCHANGED.
__global__ void pack_weights(const float* __restrict__ k1, const float* __restrict__ r1,
                             const float* __restrict__ k2, const float* __restrict__ r2,
                             __half2* __restrict__ ws)
{
    int idx = blockIdx.x * 256 + threadIdx.x;
    if (idx >= TOTAL_H2) return;
    float a, b;
    if (idx < G2Z_OFF) {
        // GRU1 planes: 3 x [2 kh][20 chunks][256 cols][4]
        int plane = idx / 40960;       // 0=z 1=r 2=h
        int rem   = idx % 40960;       // = cc*1024 + col*4 + q
        int cc    = rem >> 10;         // 0..39
        int col   = (rem >> 2) & 255;
        int q     = rem & 3;
        int kh    = cc / 20;
        int c     = cc - kh * 20;
        int g     = plane * 256 + col; // gate-column in [0,768)
        int pair  = (c < 4) ? ((kh * 4 + c) * 4 + q)
                            : (32 + (kh * 16 + (c - 4)) * 4 + q);
        int row0  = pair * 2;
        if (row0 < 64) { a = k1[row0 * 768 + g];        b = k1[(row0 + 1) * 768 + g]; }
        else           { a = r1[(row0 - 64) * 768 + g]; b = r1[(row0 - 63) * 768 + g]; }
    } else {
        // GRU2 planes: 3 x [4 kq][12 chunks][128 cols][4]
        int idx2  = idx - G2Z_OFF;
        int plane = idx2 / 24576;
        int rem   = idx2 % 24576;      // = cc*512 + col*4 + q
        int cc    = rem >> 9;          // 0..47
        int col   = (rem >> 2) & 127;
        int q     = rem & 3;
        int kq    = cc / 12;
        int c     = cc - kq * 12;
        int g     = plane * 128 + col; // gate-column in [0,384)
        int pair  = (c < 8) ? ((kq * 8 + c) * 4 + q)
                            : (128 + (kq * 4 + (c - 8)) * 4 + q);
        int row0  = pair * 2;
        if (row0 < 256) { a = k2[row0 * 384 + g];         b = k2[(row0 + 1) * 384 + g]; }
        else            { a = r2[(row0 - 256) * 384 + g]; b = r2[(row0 - 255) * 384 + g]; }
    }
    __half2 h;
    h.x = __float2half_rn(a);
    h.y = __float2half_rn(b);
    ws[idx] = h;
}

// 2-deep K-segment with SOFTWARE-PIPELINED ACT READS (R11): the B-half act
// reads issue at the top of the iteration (~90 cyc cover under the B weight
// issues + dots-A) and the next-A act reads issue right after the next-A
// weight loads (~full-iteration cover). R10 post-mortem: ds_read latency
// (~120 cyc) exposed right before the dots was the dominant unhidden stall.
// Peak act regs 2 -> 4 uint4 (+8 VGPR, 112 -> ~120 < the 128 wall).
// NAMED A/B buffers + #pragma unroll 1 (R1/R2 spill lesson) kept verbatim.
template <int COLS, int NCH>
__device__ __forceinline__ void seg3p(const uint4* __restrict__ pz,
                                      const uint4* __restrict__ pr,
                                      const uint4* __restrict__ ph,
                                      const unsigned int* __restrict__ act,
                                      float& az, float& ar, float& a3)
{
    static_assert(NCH % 4 == 0, "NCH must be a multiple of 4");
    uint4 a_z0 = pz[0], a_z1 = pz[COLS];
    uint4 a_r0 = pr[0], a_r1 = pr[COLS];
    uint4 a_h0 = ph[0], a_h1 = ph[COLS];
    uint4 va0 = *(const uint4*)(act);
    uint4 va1 = *(const uint4*)(act + 4);
    #pragma unroll 1
    for (int c = 0; c < NCH; c += 4) {
        const uint4* qz = pz + 2 * COLS;
        const uint4* qr = pr + 2 * COLS;
        const uint4* qh = ph + 2 * COLS;
        uint4 b_z0 = qz[0], b_z1 = qz[COLS];
        uint4 b_r0 = qr[0], b_r1 = qr[COLS];
        uint4 b_h0 = qh[0], b_h1 = qh[COLS];
        // B-half acts early: covered by the 6 load issues + dots-A below
        const uint4 vb0 = *(const uint4*)(act + 8);
        const uint4 vb1 = *(const uint4*)(act + 12);
        dot4(az, a_z0, va0); dot4(ar, a_r0, va0); dot4(a3, a_h0, va0);
        dot4(az, a_z1, va1); dot4(ar, a_r1, va1); dot4(a3, a_h1, va1);
        pz += 4 * COLS; pr += 4 * COLS; ph += 4 * COLS;
        act += 16;
        if (c + 4 < NCH) {
            a_z0 = pz[0]; a_z1 = pz[COLS];
            a_r0 = pr[0]; a_r1 = pr[COLS];
            a_h0 = ph[0]; a_h1 = ph[COLS];
            // next-A acts: ~full iteration of cover before their dots
            va0 = *(const uint4*)(act);
            va1 = *(const uint4*)(act + 4);
        }
        dot4(az, b_z0, vb0); dot4(ar, b_r0, vb0); dot4(a3, b_h0, vb0);
        dot4(az, b_z1, vb1); dot4(ar, b_r1, vb1); dot4(a3, b_h1, vb1);
    }
}

// 2-chunk straight-line segment (x-part: LDS-park half + global half)
template <int COLS>
__device__ __forceinline__ void seg_pair(const uint4* __restrict__ pz,
                                         const uint4* __restrict__ pr,
                                         const uint4* __restrict__ ph,
                                         const unsigned int* __restrict__ act,
                                         float& az, float& ar, float& a3)
{
    // acts first: their ds latency hides under the 6 weight-load issues
    const uint4 v0 = *(const uint4*)(act);
    const uint4 v1 = *(const uint4*)(act + 4);
    uint4 z0 = pz[0], z1 = pz[COLS];
    uint4 r0 = pr[0], r1 = pr[COLS];
    uint4 h0 = ph[0], h1 = ph[COLS];
    dot4(az, z0, v0); dot4(ar, r0, v0); dot4(a3, h0, v0);
    dot4(az, z1, v1); dot4(ar, r1, v1); dot4(a3, h1, v1);
}

// 256 WGs x 512 threads (8 waves/CU, grid-pinned), one batch row per WG.
// R9 base (best measured: 4718 us; 147 KB dynamic-LDS park, lane-linear park
// layout, skewed act replica) + seg3p act pipelining. R10's DMA rings REVERTED
// (ring reads re-introduced 4-way bank conflicts + vmcnt fences serialized).
// K-split: GRU1 by 2 (kh = tid&1), GRU2 by 4 (kq = tid&3); shfl_xor reduce.
// One barrier per timestep.
__global__ __launch_bounds__(512, 2)
void gru_fused(const float* __restrict__ x,
               const float* __restrict__ b1, const float* __restrict__ b2,
               const float* __restrict__ w3, const float* __restrict__ b3,
               const float* __restrict__ w4, const float* __restrict__ b4,
               const float* __restrict__ w5, const float* __restrict__ b5,
               const unsigned int* __restrict__ wp,
               float* __restrict__ out)
{
    // Parked weights: dynamic LDS, 147,456 B, lane-linear layout.
    //   lw2[(c*3+g)*512 + tid], c=0..3: GRU2 h2-part chunk kq*12+8+c, col c2 (98,304 B)
    //   lw1[(c*3+g)*512 + tid], c=0..1: GRU1 x-part  chunk kh*20+c,   col j  (49,152 B)
    extern __shared__ __align__(16) uint4 lwdyn[];
    uint4* lw2 = lwdyn;
    uint4* lw1 = lwdyn + 6144;
    // fp16 activation pair buffers (uint = one half2), double-buffered. (static)
    __shared__ __align__(16) unsigned int act1[2][160];   // [0..31]=x(t), [32..159]=h1
    __shared__ __align__(16) unsigned int act2[2][64];    // h2
    __shared__ __align__(16) unsigned int act1s[2][160];  // skewed h1 replica: kq block at kq*40
    __shared__ float h2fin[NU2];
    __shared__ float d3[64];
    __shared__ float d4[32];

    const int tid = threadIdx.x;
    const int row = blockIdx.x;
    const int j   = tid >> 1;       // GRU1 column (0..255)
    const int kh  = tid & 1;        // GRU1 K-half
    const int c2  = tid >> 2;       // GRU2 column (0..127)
    const int kq  = tid & 3;        // GRU2 K-quarter

    const uint4* wp4 = (const uint4*)wp;

    // ---- park weights into LDS (once; lane-linear layout) ----
    // lw2[i]: i = (c*3+g)*512 + tid  <-  GRU2 plane g, chunk kq*12+8+c, col c2
    for (int i = tid; i < 6144; i += 512) {
        int cg = i >> 9;               // tid < 512 so i>>9 == block index
        int c  = cg / 3, g = cg - 3 * c;
        lw2[i] = wp4[G2Z_U4 + g * 6144 + (kq * 12 + 8 + c) * 128 + c2];
    }
    // lw1[i]: i = (c*3+g)*512 + tid  <-  GRU1 plane g, chunk kh*20+c, col j
    for (int i = tid; i < 3072; i += 512) {
        int cg = i >> 9;
        int c  = cg / 3, g = cg - 3 * c;
        lw1[i] = wp4[G1Z_U4 + g * 10240 + (kh * 20 + c) * 256 + j];
    }

    for (int i = tid; i < 2 * 160; i += 512) (&act1[0][0])[i]  = 0u;
    for (int i = tid; i < 2 * 64;  i += 512) (&act2[0][0])[i]  = 0u;
    for (int i = tid; i < 2 * 160; i += 512) (&act1s[0][0])[i] = 0u;

    // GRU1 biases (z,r folded; h kept split for reset_after), counted once via kh mask
    const float bm1  = (kh == 0) ? 1.0f : 0.0f;
    const float bz1  = (b1[j] + b1[768 + j]) * bm1;
    const float br1  = (b1[256 + j] + b1[1024 + j]) * bm1;
    const float bxh1 = b1[512 + j] * bm1;
    const float brh1 = b1[1280 + j] * bm1;
    // GRU2 biases, counted once via kq mask
    const float bm2  = (kq == 0) ? 1.0f : 0.0f;
    const float bz2  = (b2[c2] + b2[384 + c2]) * bm2;
    const float br2  = (b2[128 + c2] + b2[512 + c2]) * bm2;
    const float bxh2 = b2[256 + c2] * bm2;
    const float brh2 = b2[640 + c2] * bm2;

    // global weight bases (per thread column)
    const uint4* g1z = wp4 + G1Z_U4 + (kh * 20) * 256 + j;
    const uint4* g1r = wp4 + G1R_U4 + (kh * 20) * 256 + j;
    const uint4* g1h = wp4 + G1H_U4 + (kh * 20) * 256 + j;
    const uint4* g2z = wp4 + G2Z_U4 + (kq * 12) * 128 + c2;
    const uint4* g2r = wp4 + G2R_U4 + (kq * 12) * 128 + c2;
    const uint4* g2h = wp4 + G2H_U4 + (kq * 12) * 128 + c2;
    // LDS weight bases (lane-linear: gate stride 512, chunk stride 1536 uint4)
    const uint4* l2 = lw2 + tid;
    const uint4* l1 = lw1 + tid;

    __syncthreads();   // parked weights + zeros visible

    if (tid < FEAT) {
        float x0 = x[(size_t)row * TSEQ * FEAT + tid];
        float xb = __shfl_xor(x0, 1);
        if ((tid & 1) == 0) act1[0][tid >> 1] = pack2(x0, xb);
    }
    __syncthreads();

    float hp1 = 0.0f;   // h1 previous state, col j (redundant on the lane pair)
    float hp2 = 0.0f;   // h2 previous state, col c2 (redundant on the lane quad)

    for (int t = 0; t < TSEQ; ++t) {
        const int cur = t & 1, nb = cur ^ 1;

        // prefetch next x into registers (packed to LDS before the barrier)
        float xpre = 0.0f;
        if (t + 1 < TSEQ && tid < FEAT)
            xpre = x[(size_t)row * TSEQ * FEAT + (t + 1) * FEAT + tid];

        // ---------------- GRU1: reads act1[cur]; writes act1[nb] ----------------
        float az = bz1, ar = br1, aA = bxh1, aB = brh1;
        // x-part: chunks 0-1 from park (lane-linear), chunks 2-3 from global
        seg_pair<1536>(l1, l1 + 512, l1 + 1024,
                       &act1[cur][kh * 16], az, ar, aA);
        seg_pair<256>(g1z + 2 * 256, g1r + 2 * 256, g1h + 2 * 256,
                      &act1[cur][kh * 16 + 8], az, ar, aA);
        // h-part: 16 chunks from global, act-pipelined
        seg3p<256, 16>(g1z + 4 * 256, g1r + 4 * 256, g1h + 4 * 256,
                       &act1[cur][32 + kh * 64], az, ar, aB);
        az += __shfl_xor(az, 1);
        ar += __shfl_xor(ar, 1);
        aA += __shfl_xor(aA, 1);
        aB += __shfl_xor(aB, 1);
        {
            const float z  = sigmoid_f(az);
            const float rg = sigmoid_f(ar);
            const float hh = tanh_f(aA + rg * aB);
            const float hn = z * hp1 + (1.0f - z) * hh;
            hp1 = hn;
            const float hnb = __shfl_xor(hn, 2);   // partner column (2m+1) on lane 4m
            if ((tid & 3) == 0) {
                const unsigned int pk = pack2(hn, hnb);
                const int p = tid >> 2;                    // pair index 0..127
                act1[nb][32 + p] = pk;
                act1s[nb][(p >> 5) * 40 + (p & 31)] = pk;  // skewed replica for GRU2
            }
        }
        if (t + 1 < TSEQ && tid < FEAT) {
            float xb = __shfl_xor(xpre, 1);
            if ((tid & 1) == 0) act1[nb][tid >> 1] = pack2(xpre, xb);
        }
        __syncthreads();   // THE one barrier: act1[nb]/act1s[nb] (h1(t)) + x(t+1) visible

        // ---------------- GRU2: reads act1s[nb] h-part, act2[cur]; writes act2[nb] ----------------
        float az2 = bz2, ar2 = br2, aA2 = bxh2, aB2 = brh2;
        // h1-part: 8 chunks from global, act from skewed replica (bank-spread)
        seg3p<128, 8>(g2z, g2r, g2h, &act1s[nb][kq * 40], az2, ar2, aA2);
        // h2-part: 4 chunks from LDS (lane-linear), act-pipelined
        seg3p<1536, 4>(l2, l2 + 512, l2 + 1024,
                       &act2[cur][kq * 16], az2, ar2, aB2);
        az2 += __shfl_xor(az2, 1); az2 += __shfl_xor(az2, 2);
        ar2 += __shfl_xor(ar2, 1); ar2 += __shfl_xor(ar2, 2);
        aA2 += __shfl_xor(aA2, 1); aA2 += __shfl_xor(aA2, 2);
        aB2 += __shfl_xor(aB2, 1); aB2 += __shfl_xor(aB2, 2);
        {
            const float z2v = sigmoid_f(az2);
            const float rg2 = sigmoid_f(ar2);
            const float hh2 = tanh_f(aA2 + rg2 * aB2);
            const float hn2 = z2v * hp2 + (1.0f - z2v) * hh2;
            hp2 = hn2;
            const float hnb2 = __shfl_xor(hn2, 4); // partner column (2m+1) on lane 8m
            if ((tid & 7) == 0) act2[nb][tid >> 3] = pack2(hn2, hnb2);
        }
        // no second barrier: next step's barrier covers act2[nb] visibility;
        // all WAR hazards are buffer-separated (same discipline as proven kernel)
    }

    if ((tid & 3) == 0) h2fin[c2] = hp2;   // final h2 state, fp32
    __syncthreads();

    // ---------------- dense head: h2 -> 64 -> 32 -> 24 ----------------
    if (tid < 64) {
        float a = b3[tid];
        #pragma unroll 4
        for (int u = 0; u < NU2; ++u) a += h2fin[u] * w3[u * 64 + tid];
        d3[tid] = a;
    }
    __syncthreads();
    if (tid < 32) {
        float a = b4[tid];
        #pragma unroll 4
        for (int u = 0; u < 64; ++u) a += d3[u] * w4[u * 32 + tid];
        d4[tid] = a;
    }
    __syncthreads();
    if (tid < 24) {
        float a = b5[tid];
        #pragma unroll 4
        for (int u = 0; u < 32; ++u) a += d4[u] * w5[u * 24 + tid];
        out[(size_t)row * 24 + tid] = a;
    }
}

extern "C" void kernel_launch(void* const* d_in, const int* in_sizes, int n_in,
                              void* d_out, int out_size, void* d_ws, size_t ws_size,
                              hipStream_t stream) {
    (void)in_sizes; (void)n_in; (void)ws_size; (void)out_size;
    const float* x  = (const float*)d_in[0];
    const float* k1 = (const float*)d_in[1];
    const float* r1 = (const float*)d_in[2];
    const float* b1 = (const float*)d_in[3];
    const float* k2 = (const float*)d_in[4];
    const float* r2 = (const float*)d_in[5];
    const float* b2 = (const float*)d_in[6];
    const float* w3 = (const float*)d_in[7];
    const float* b3 = (const float*)d_in[8];
    const float* w4 = (const float*)d_in[9];
    const float* b4 = (const float*)d_in[10];
    const float* w5 = (const float*)d_in[11];
    const float* b5 = (const float*)d_in[12];
    float* out = (float*)d_out;

    // Opt in to >64 KB dynamic LDS (host-side, executes at capture time).
    static bool lds_attr_set = false;
    if (!lds_attr_set) {
        (void)hipFuncSetAttribute((const void*)gru_fused,
                                  hipFuncAttributeMaxDynamicSharedMemorySize,
                                  LDS_PARK_BYTES);
        lds_attr_set = true;
    }

    hipLaunchKernelGGL(pack_weights, dim3((TOTAL_H2 + 255) / 256), dim3(256), 0, stream,
                       k1, r1, k2, r2, (__half2*)d_ws);
    hipLaunchKernelGGL(gru_fused, dim3(BATCH), dim3(512), LDS_PARK_BYTES, stream,
                       x, b1, b2, w3, b3, w4, b4, w5, b5,
                       (const unsigned int*)d_ws, out);
}

// Round 13
// 4049.949 us; speedup vs baseline: 1.5602x; 1.1709x over previous
//
#include <hip/hip_runtime.h>
#include <hip/hip_fp16.h>
#include <math.h>

// Problem constants
#define BATCH 256
#define TSEQ  512
#define FEAT  64
#define NU1   256
#define NU2   128

// fp16 packed planes (R3 layout, unchanged):
// GRU1 plane (per gate): [2 kh][20 chunks][256 cols][4 half2]; chunk = 256 uint4
//   chunks 0..3 = x rows, chunks 4..19 = h1 rows (fp16 h-part DEAD in FP8 mode)
// GRU2 plane (per gate): [4 kq][12 chunks][128 cols][4]
#define G1Z_U4 0
#define G1R_U4 10240
#define G1H_U4 20480
#define G2Z_U4 30720
#define G2R_U4 36864
#define G2H_U4 43008
#define TOTAL_H2 196608            // 786,432 B of fp16 planes

// FP8 reclaim (R13): fp8 GRU1-h planes overwrite the dead fp16 GRU1-h region.
// Block (g,kh): uint4 base = g*10240 + kh*5120 + 1024, 8 fchunks x 256 cols x 16B
// (fchunk f = K-rows kh*128 + f*16 .. +15; byte b of a block = row ..+b).
// fp8 data ends at uint4 3071 of each block; uint4 3072..5119 remain dead.
// Scales (768 floats = 192 uint4) live INSIDE g0/kh0's dead tail at uint4 3072
// (byte 49152) -> NO workspace bytes needed beyond the proven 786,432.
#define FP8_SC_BYTE 49152

#define LDS_PARK_BYTES (9216 * 16)   // 147,456 B dynamic LDS (parks, R8/R9-proven)

typedef _Float16 h2f __attribute__((ext_vector_type(2)));
typedef float f32x2 __attribute__((ext_vector_type(2)));

__device__ __forceinline__ float sigmoid_f(float v) {
    return 1.0f / (1.0f + __expf(-v));
}
__device__ __forceinline__ float tanh_f(float v) {
    float c = fminf(fmaxf(v, -15.0f), 15.0f);
    float e = __expf(2.0f * c);
    return (e - 1.0f) / (e + 1.0f);
}
__device__ __forceinline__ h2f bch2(unsigned int u) {
    return __builtin_bit_cast(h2f, u);
}
__device__ __forceinline__ unsigned int pack2(float a, float b) {
    h2f v; v.x = (_Float16)a; v.y = (_Float16)b;
    return __builtin_bit_cast(unsigned int, v);
}
__device__ __forceinline__ void dot4(float& acc, uint4 w, uint4 a) {
    acc = __builtin_amdgcn_fdot2(bch2(w.x), bch2(a.x), acc, false);
    acc = __builtin_amdgcn_fdot2(bch2(w.y), bch2(a.y), acc, false);
    acc = __builtin_amdgcn_fdot2(bch2(w.z), bch2(a.z), acc, false);
    acc = __builtin_amdgcn_fdot2(bch2(w.w), bch2(a.w), acc, false);
}

// ---- fp8 e4m3fn decode ----
// R12 failure root cause: the amdgcn cvt builtins take an IMMEDIATE word-select
// (clang signature "V2fiIb") -- passing a runtime bool is a hard compile error.
// Fix: separate _lo/_hi helpers with literal immediates at the builtin call.
#if __has_builtin(__builtin_amdgcn_cvt_pk_f32_fp8)
__device__ __forceinline__ f32x2 cvtpk8_lo(unsigned int u) {
    return __builtin_amdgcn_cvt_pk_f32_fp8((int)u, false);
}
__device__ __forceinline__ f32x2 cvtpk8_hi(unsigned int u) {
    return __builtin_amdgcn_cvt_pk_f32_fp8((int)u, true);
}
#else
__device__ __forceinline__ float fp8dec1(unsigned int b) {
    // e4m3fn -> f32, exact for normals AND subnormals: reinterpret 7-bit
    // exp:man as an f32 bit pattern, rescale by 2^120 (subnormal mul is exact)
    float m = __uint_as_float((b & 0x7fu) << 20) * 0x1p+120f;
    return (b & 0x80u) ? -m : m;
}
__device__ __forceinline__ f32x2 cvtpk8_lo(unsigned int u) {
    f32x2 r; r.x = fp8dec1(u & 0xffu); r.y = fp8dec1((u >> 8) & 0xffu);
    return r;
}
__device__ __forceinline__ f32x2 cvtpk8_hi(unsigned int u) {
    f32x2 r; r.x = fp8dec1((u >> 16) & 0xffu); r.y = fp8dec1((u >> 24) & 0xffu);
    return r;
}
#endif

// acc += dot of 16 fp8 weights (one uint4) with 16 f32 acts
__device__ __forceinline__ void dot16f8(float& acc, uint4 w,
                                        float4 a0, float4 a1, float4 a2, float4 a3) {
    f32x2 l, h;
    l = cvtpk8_lo(w.x); h = cvtpk8_hi(w.x);
    acc = fmaf(l.x, a0.x, acc); acc = fmaf(l.y, a0.y, acc);
    acc = fmaf(h.x, a0.z, acc); acc = fmaf(h.y, a0.w, acc);
    l = cvtpk8_lo(w.y); h = cvtpk8_hi(w.y);
    acc = fmaf(l.x, a1.x, acc); acc = fmaf(l.y, a1.y, acc);
    acc = fmaf(h.x, a1.z, acc); acc = fmaf(h.y, a1.w, acc);
    l = cvtpk8_lo(w.z); h = cvtpk8_hi(w.z);
    acc = fmaf(l.x, a2.x, acc); acc = fmaf(l.y, a2.y, acc);
    acc = fmaf(h.x, a2.z, acc); acc = fmaf(h.y, a2.w, acc);
    l = cvtpk8_lo(w.w); h = cvtpk8_hi(w.w);
    acc = fmaf(l.x, a3.x, acc); acc = fmaf(l.y, a3.y, acc);
    acc = fmaf(h.x, a3.z, acc); acc = fmaf(h.y, a3.w, acc);
}

// e4m3fn RNE encode (cold path; no hip_fp8.h dependency)
__device__ unsigned char enc_e4m3(float v) {
    float a = fabsf(v);
    if (!(a > 0.0f)) return 0;              // 0 / -0 / NaN-in -> +0
    unsigned s = (__float_as_uint(v) >> 31) ? 0x80u : 0u;
    a = fminf(a, 448.0f);
    int e; float m = frexpf(a, &e);         // a = m * 2^e, m in [0.5,1)
    int E = e - 1; float sig = 2.0f * m;    // a = sig * 2^E, sig in [1,2)
    if (E < -6) {                            // subnormal: units of 2^-9
        float q = rintf(a * 512.0f);
        if (q >= 8.0f) return (unsigned char)(s | 0x08u);
        return (unsigned char)(s | (unsigned)q);
    }
    float f = rintf((sig - 1.0f) * 8.0f);
    if (f >= 8.0f) { E += 1; f = 0.0f; }
    if (E > 8) return (unsigned char)(s | 0x7Eu);   // clamp to 448
    return (unsigned char)(s | ((unsigned)(E + 7) << 3) | (unsigned)f);
}

// ---------------- fp16 weight packing (R3 layout, UNCHANGED) ----------------
__global__ void pack_weights(const float* __restrict__ k1, const float* __restrict__ r1,
                             const float* __restrict__ k2, const float* __restrict__ r2,
                             __half2* __restrict__ ws)
{
    int idx = blockIdx.x * 256 + threadIdx.x;
    if (idx >= TOTAL_H2) return;
    float a, b;
    if (idx < 122880) {
        int plane = idx / 40960;
        int rem   = idx % 40960;
        int cc    = rem >> 10;
        int col   = (rem >> 2) & 255;
        int q     = rem & 3;
        int kh    = cc / 20;
        int c     = cc - kh * 20;
        int g     = plane * 256 + col;
        int pair  = (c < 4) ? ((kh * 4 + c) * 4 + q)
                            : (32 + (kh * 16 + (c - 4)) * 4 + q);
        int row0  = pair * 2;
        if (row0 < 64) { a = k1[row0 * 768 + g];        b = k1[(row0 + 1) * 768 + g]; }
        else           { a = r1[(row0 - 64) * 768 + g]; b = r1[(row0 - 63) * 768 + g]; }
    } else {
        int idx2  = idx - 122880;
        int plane = idx2 / 24576;
        int rem   = idx2 % 24576;
        int cc    = rem >> 9;
        int col   = (rem >> 2) & 127;
        int q     = rem & 3;
        int kq    = cc / 12;
        int c     = cc - kq * 12;
        int g     = plane * 128 + col;
        int pair  = (c < 8) ? ((kq * 8 + c) * 4 + q)
                            : (128 + (kq * 4 + (c - 8)) * 4 + q);
        int row0  = pair * 2;
        if (row0 < 256) { a = k2[row0 * 384 + g];         b = k2[(row0 + 1) * 384 + g]; }
        else            { a = r2[(row0 - 256) * 384 + g]; b = r2[(row0 - 255) * 384 + g]; }
    }
    __half2 h;
    h.x = __float2half_rn(a);
    h.y = __float2half_rn(b);
    ws[idx] = h;
}

// ---- fp8 GRU1-h packing: per-(gate,col) absmax scale + e4m3 quantize ----
// Runs AFTER pack_weights; overwrites the dead fp16 GRU1-h region. Scales go
// into g0/kh0's dead tail (byte 49152) -- no extra workspace bytes.
__global__ void pack_fp8(const float* __restrict__ r1, char* __restrict__ wsb)
{
    int g   = blockIdx.x;     // gate 0..2
    int col = threadIdx.x;    // 0..255
    float mx = 0.0f;
    for (int r = 0; r < 256; ++r)
        mx = fmaxf(mx, fabsf(r1[r * 768 + g * 256 + col]));
    float s = fmaxf(mx * (1.0f / 448.0f), 1e-30f);
    ((float*)(wsb + FP8_SC_BYTE))[g * 256 + col] = s;
    float inv = 1.0f / s;
    for (int r = 0; r < 256; ++r) {
        float w = r1[r * 768 + g * 256 + col] * inv;
        int kh = r >> 7, f = (r >> 4) & 7, b = r & 15;
        wsb[(size_t)(g * 10240 + kh * 5120 + 1024 + f * 256 + col) * 16 + b] =
            (char)enc_e4m3(w);
    }
}

// 2-deep fp16 K-segment (R11's seg3p: act-pipelined, named A/B, unroll 1)
template <int COLS, int NCH>
__device__ __forceinline__ void seg3p(const uint4* __restrict__ pz,
                                      const uint4* __restrict__ pr,
                                      const uint4* __restrict__ ph,
                                      const unsigned int* __restrict__ act,
                                      float& az, float& ar, float& a3)
{
    static_assert(NCH % 4 == 0, "NCH must be a multiple of 4");
    uint4 a_z0 = pz[0], a_z1 = pz[COLS];
    uint4 a_r0 = pr[0], a_r1 = pr[COLS];
    uint4 a_h0 = ph[0], a_h1 = ph[COLS];
    uint4 va0 = *(const uint4*)(act);
    uint4 va1 = *(const uint4*)(act + 4);
    #pragma unroll 1
    for (int c = 0; c < NCH; c += 4) {
        const uint4* qz = pz + 2 * COLS;
        const uint4* qr = pr + 2 * COLS;
        const uint4* qh = ph + 2 * COLS;
        uint4 b_z0 = qz[0], b_z1 = qz[COLS];
        uint4 b_r0 = qr[0], b_r1 = qr[COLS];
        uint4 b_h0 = qh[0], b_h1 = qh[COLS];
        const uint4 vb0 = *(const uint4*)(act + 8);
        const uint4 vb1 = *(const uint4*)(act + 12);
        dot4(az, a_z0, va0); dot4(ar, a_r0, va0); dot4(a3, a_h0, va0);
        dot4(az, a_z1, va1); dot4(ar, a_r1, va1); dot4(a3, a_h1, va1);
        pz += 4 * COLS; pr += 4 * COLS; ph += 4 * COLS;
        act += 16;
        if (c + 4 < NCH) {
            a_z0 = pz[0]; a_z1 = pz[COLS];
            a_r0 = pr[0]; a_r1 = pr[COLS];
            a_h0 = ph[0]; a_h1 = ph[COLS];
            va0 = *(const uint4*)(act);
            va1 = *(const uint4*)(act + 4);
        }
        dot4(az, b_z0, vb0); dot4(ar, b_r0, vb0); dot4(a3, b_h0, vb0);
        dot4(az, b_z1, vb1); dot4(ar, b_r1, vb1); dot4(a3, b_h1, vb1);
    }
}

template <int COLS>
__device__ __forceinline__ void seg_pair(const uint4* __restrict__ pz,
                                         const uint4* __restrict__ pr,
                                         const uint4* __restrict__ ph,
                                         const unsigned int* __restrict__ act,
                                         float& az, float& ar, float& a3)
{
    const uint4 v0 = *(const uint4*)(act);
    const uint4 v1 = *(const uint4*)(act + 4);
    uint4 z0 = pz[0], z1 = pz[COLS];
    uint4 r0 = pr[0], r1 = pr[COLS];
    uint4 h0 = ph[0], h1 = ph[COLS];
    dot4(az, z0, v0); dot4(ar, r0, v0); dot4(a3, h0, v0);
    dot4(az, z1, v1); dot4(ar, r1, v1); dot4(a3, h1, v1);
}

// 256 WGs x 512 threads, one batch row per WG. R9/R11 base (4718 us proven).
// FP8=true: GRU1-h weights stream as e4m3 (384 -> 192 KB/step; global total
// 639 -> 447 KB/step), decoded via HW cvt (or exact bit-trick), per-(gate,col)
// scale folded once per segment. FP8=false: exact R11 (revert lever).
template <bool FP8>
__global__ __launch_bounds__(512, 2)
void gru_fused(const float* __restrict__ x,
               const float* __restrict__ b1, const float* __restrict__ b2,
               const float* __restrict__ w3, const float* __restrict__ b3,
               const float* __restrict__ w4, const float* __restrict__ b4,
               const float* __restrict__ w5, const float* __restrict__ b5,
               const unsigned int* __restrict__ wp,
               float* __restrict__ out)
{
    extern __shared__ __align__(16) uint4 lwdyn[];   // parks (R8/R9 proven)
    uint4* lw2 = lwdyn;          // GRU2 h2-part, lane-linear
    uint4* lw1 = lwdyn + 6144;   // GRU1 x-part chunks 0-1, lane-linear
    __shared__ __align__(16) unsigned int act1[2][160];
    __shared__ __align__(16) unsigned int act2[2][64];
    __shared__ __align__(16) unsigned int act1s[2][160];  // skewed h1 (GRU2)
    __shared__ __align__(16) float act1f[2][256];         // f32 h1 (FP8 path)
    __shared__ float h2fin[NU2];
    __shared__ float d3[64];
    __shared__ float d4[32];

    const int tid = threadIdx.x;
    const int row = blockIdx.x;
    const int j   = tid >> 1;       // GRU1 column
    const int kh  = tid & 1;        // GRU1 K-half
    const int c2  = tid >> 2;       // GRU2 column
    const int kq  = tid & 3;        // GRU2 K-quarter

    const uint4* wp4 = (const uint4*)wp;
    const char*  wpb = (const char*)wp;

    for (int i = tid; i < 6144; i += 512) {
        int cg = i >> 9;
        int c  = cg / 3, g = cg - 3 * c;
        lw2[i] = wp4[G2Z_U4 + g * 6144 + (kq * 12 + 8 + c) * 128 + c2];
    }
    for (int i = tid; i < 3072; i += 512) {
        int cg = i >> 9;
        int c  = cg / 3, g = cg - 3 * c;
        lw1[i] = wp4[G1Z_U4 + g * 10240 + (kh * 20 + c) * 256 + j];
    }
    for (int i = tid; i < 2 * 160; i += 512) (&act1[0][0])[i]  = 0u;
    for (int i = tid; i < 2 * 64;  i += 512) (&act2[0][0])[i]  = 0u;
    for (int i = tid; i < 2 * 160; i += 512) (&act1s[0][0])[i] = 0u;
    for (int i = tid; i < 2 * 256; i += 512) (&act1f[0][0])[i] = 0.0f;

    const float bm1  = (kh == 0) ? 1.0f : 0.0f;
    const float bz1  = (b1[j] + b1[768 + j]) * bm1;
    const float br1  = (b1[256 + j] + b1[1024 + j]) * bm1;
    const float bxh1 = b1[512 + j] * bm1;
    const float brh1 = b1[1280 + j] * bm1;
    const float bm2  = (kq == 0) ? 1.0f : 0.0f;
    const float bz2  = (b2[c2] + b2[384 + c2]) * bm2;
    const float br2  = (b2[128 + c2] + b2[512 + c2]) * bm2;
    const float bxh2 = b2[256 + c2] * bm2;
    const float brh2 = b2[640 + c2] * bm2;

    const uint4* g1z = wp4 + G1Z_U4 + (kh * 20) * 256 + j;
    const uint4* g1r = wp4 + G1R_U4 + (kh * 20) * 256 + j;
    const uint4* g1h = wp4 + G1H_U4 + (kh * 20) * 256 + j;
    const uint4* g2z = wp4 + G2Z_U4 + (kq * 12) * 128 + c2;
    const uint4* g2r = wp4 + G2R_U4 + (kq * 12) * 128 + c2;
    const uint4* g2h = wp4 + G2H_U4 + (kq * 12) * 128 + c2;
    const uint4* l2 = lw2 + tid;
    const uint4* l1 = lw1 + tid;

    // fp8 GRU1-h bases + scales (FP8 path only)
    const uint4* q8zb = wp4 + kh * 5120 + 1024 + j;   // gate stride 10240 uint4
    float s_z = 0.0f, s_r = 0.0f, s_h = 0.0f;
    if constexpr (FP8) {
        const float* sc = (const float*)(wpb + FP8_SC_BYTE);
        s_z = sc[j]; s_r = sc[256 + j]; s_h = sc[512 + j];
    }

    __syncthreads();

    if (tid < FEAT) {
        float x0 = x[(size_t)row * TSEQ * FEAT + tid];
        float xb = __shfl_xor(x0, 1);
        if ((tid & 1) == 0) act1[0][tid >> 1] = pack2(x0, xb);
    }
    __syncthreads();

    float hp1 = 0.0f;
    float hp2 = 0.0f;

    for (int t = 0; t < TSEQ; ++t) {
        const int cur = t & 1, nb = cur ^ 1;

        float xpre = 0.0f;
        if (t + 1 < TSEQ && tid < FEAT)
            xpre = x[(size_t)row * TSEQ * FEAT + (t + 1) * FEAT + tid];

        // ---------------- GRU1 ----------------
        float az = bz1, ar = br1, aA = bxh1, aB = brh1;
        seg_pair<1536>(l1, l1 + 512, l1 + 1024,
                       &act1[cur][kh * 16], az, ar, aA);
        seg_pair<256>(g1z + 2 * 256, g1r + 2 * 256, g1h + 2 * 256,
                      &act1[cur][kh * 16 + 8], az, ar, aA);
        if constexpr (FP8) {
            // h-part: 8 fchunks of fp8, A/B 2-fchunk pipeline (6 in flight)
            float z8 = 0.0f, r8 = 0.0f, h8 = 0.0f;
            const float* af = &act1f[cur][kh * 128];
            const uint4* qz = q8zb;
            uint4 a_z0 = qz[0], a_z1 = qz[256];
            uint4 a_r0 = qz[10240], a_r1 = qz[10240 + 256];
            uint4 a_h0 = qz[20480], a_h1 = qz[20480 + 256];
            #pragma unroll 1
            for (int f = 0; f < 8; f += 4) {
                const uint4* bz = qz + 2 * 256;
                uint4 b_z0 = bz[0], b_z1 = bz[256];
                uint4 b_r0 = bz[10240], b_r1 = bz[10240 + 256];
                uint4 b_h0 = bz[20480], b_h1 = bz[20480 + 256];
                {
                    const float4 a0 = *(const float4*)(af);
                    const float4 a1 = *(const float4*)(af + 4);
                    const float4 a2 = *(const float4*)(af + 8);
                    const float4 a3 = *(const float4*)(af + 12);
                    dot16f8(z8, a_z0, a0, a1, a2, a3);
                    dot16f8(r8, a_r0, a0, a1, a2, a3);
                    dot16f8(h8, a_h0, a0, a1, a2, a3);
                }
                {
                    const float4 a0 = *(const float4*)(af + 16);
                    const float4 a1 = *(const float4*)(af + 20);
                    const float4 a2 = *(const float4*)(af + 24);
                    const float4 a3 = *(const float4*)(af + 28);
                    dot16f8(z8, a_z1, a0, a1, a2, a3);
                    dot16f8(r8, a_r1, a0, a1, a2, a3);
                    dot16f8(h8, a_h1, a0, a1, a2, a3);
                }
                qz += 4 * 256;
                if (f + 4 < 8) {
                    a_z0 = qz[0]; a_z1 = qz[256];
                    a_r0 = qz[10240]; a_r1 = qz[10240 + 256];
                    a_h0 = qz[20480]; a_h1 = qz[20480 + 256];
                }
                {
                    const float4 a0 = *(const float4*)(af + 32);
                    const float4 a1 = *(const float4*)(af + 36);
                    const float4 a2 = *(const float4*)(af + 40);
                    const float4 a3 = *(const float4*)(af + 44);
                    dot16f8(z8, b_z0, a0, a1, a2, a3);
                    dot16f8(r8, b_r0, a0, a1, a2, a3);
                    dot16f8(h8, b_h0, a0, a1, a2, a3);
                }
                {
                    const float4 a0 = *(const float4*)(af + 48);
                    const float4 a1 = *(const float4*)(af + 52);
                    const float4 a2 = *(const float4*)(af + 56);
                    const float4 a3 = *(const float4*)(af + 60);
                    dot16f8(z8, b_z1, a0, a1, a2, a3);
                    dot16f8(r8, b_r1, a0, a1, a2, a3);
                    dot16f8(h8, b_h1, a0, a1, a2, a3);
                }
                af += 64;
            }
            az = fmaf(s_z, z8, az);
            ar = fmaf(s_r, r8, ar);
            aB = fmaf(s_h, h8, aB);
        } else {
            seg3p<256, 16>(g1z + 4 * 256, g1r + 4 * 256, g1h + 4 * 256,
                           &act1[cur][32 + kh * 64], az, ar, aB);
        }
        az += __shfl_xor(az, 1);
        ar += __shfl_xor(ar, 1);
        aA += __shfl_xor(aA, 1);
        aB += __shfl_xor(aB, 1);
        {
            const float z  = sigmoid_f(az);
            const float rg = sigmoid_f(ar);
            const float hh = tanh_f(aA + rg * aB);
            const float hn = z * hp1 + (1.0f - z) * hh;
            hp1 = hn;
            if constexpr (FP8) {
                if (kh == 0) act1f[nb][j] = hn;   // f32 replica for fp8 dots
            }
            const float hnb = __shfl_xor(hn, 2);
            if ((tid & 3) == 0) {
                const unsigned int pk = pack2(hn, hnb);
                const int p = tid >> 2;
                act1[nb][32 + p] = pk;
                act1s[nb][(p >> 5) * 40 + (p & 31)] = pk;
            }
        }
        if (t + 1 < TSEQ && tid < FEAT) {
            float xb = __shfl_xor(xpre, 1);
            if ((tid & 1) == 0) act1[nb][tid >> 1] = pack2(xpre, xb);
        }
        __syncthreads();

        // ---------------- GRU2 (unchanged R9/R11 path) ----------------
        float az2 = bz2, ar2 = br2, aA2 = bxh2, aB2 = brh2;
        seg3p<128, 8>(g2z, g2r, g2h, &act1s[nb][kq * 40], az2, ar2, aA2);
        seg3p<1536, 4>(l2, l2 + 512, l2 + 1024,
                       &act2[cur][kq * 16], az2, ar2, aB2);
        az2 += __shfl_xor(az2, 1); az2 += __shfl_xor(az2, 2);
        ar2 += __shfl_xor(ar2, 1); ar2 += __shfl_xor(ar2, 2);
        aA2 += __shfl_xor(aA2, 1); aA2 += __shfl_xor(aA2, 2);
        aB2 += __shfl_xor(aB2, 1); aB2 += __shfl_xor(aB2, 2);
        {
            const float z2v = sigmoid_f(az2);
            const float rg2 = sigmoid_f(ar2);
            const float hh2 = tanh_f(aA2 + rg2 * aB2);
            const float hn2 = z2v * hp2 + (1.0f - z2v) * hh2;
            hp2 = hn2;
            const float hnb2 = __shfl_xor(hn2, 4);
            if ((tid & 7) == 0) act2[nb][tid >> 3] = pack2(hn2, hnb2);
        }
    }

    if ((tid & 3) == 0) h2fin[c2] = hp2;
    __syncthreads();

    if (tid < 64) {
        float a = b3[tid];
        #pragma unroll 4
        for (int u = 0; u < NU2; ++u) a += h2fin[u] * w3[u * 64 + tid];
        d3[tid] = a;
    }
    __syncthreads();
    if (tid < 32) {
        float a = b4[tid];
        #pragma unroll 4
        for (int u = 0; u < 64; ++u) a += d3[u] * w4[u * 32 + tid];
        d4[tid] = a;
    }
    __syncthreads();
    if (tid < 24) {
        float a = b5[tid];
        #pragma unroll 4
        for (int u = 0; u < 32; ++u) a += d4[u] * w5[u * 24 + tid];
        out[(size_t)row * 24 + tid] = a;
    }
}

extern "C" void kernel_launch(void* const* d_in, const int* in_sizes, int n_in,
                              void* d_out, int out_size, void* d_ws, size_t ws_size,
                              hipStream_t stream) {
    (void)in_sizes; (void)n_in; (void)out_size; (void)ws_size;
    const float* x  = (const float*)d_in[0];
    const float* k1 = (const float*)d_in[1];
    const float* r1 = (const float*)d_in[2];
    const float* b1 = (const float*)d_in[3];
    const float* k2 = (const float*)d_in[4];
    const float* r2 = (const float*)d_in[5];
    const float* b2 = (const float*)d_in[6];
    const float* w3 = (const float*)d_in[7];
    const float* b3 = (const float*)d_in[8];
    const float* w4 = (const float*)d_in[9];
    const float* b4 = (const float*)d_in[10];
    const float* w5 = (const float*)d_in[11];
    const float* b5 = (const float*)d_in[12];
    float* out = (float*)d_out;

    static bool lds_attr_set = false;
    if (!lds_attr_set) {
        (void)hipFuncSetAttribute((const void*)gru_fused<true>,
                                  hipFuncAttributeMaxDynamicSharedMemorySize,
                                  LDS_PARK_BYTES);
        (void)hipFuncSetAttribute((const void*)gru_fused<false>,
                                  hipFuncAttributeMaxDynamicSharedMemorySize,
                                  LDS_PARK_BYTES);
        lds_attr_set = true;
    }

    hipLaunchKernelGGL(pack_weights, dim3((TOTAL_H2 + 255) / 256), dim3(256), 0, stream,
                       k1, r1, k2, r2, (__half2*)d_ws);
    hipLaunchKernelGGL(pack_fp8, dim3(3), dim3(256), 0, stream,
                       r1, (char*)d_ws);
    hipLaunchKernelGGL((gru_fused<true>), dim3(BATCH), dim3(512), LDS_PARK_BYTES,
                       stream, x, b1, b2, w3, b3, w4, b4, w5, b5,
                       (const unsigned int*)d_ws, out);
}